// Round 16
// baseline (130.653 us; speedup 1.0000x reference)
//
#include <hip/hip_runtime.h>

#define U_CNT 16384
#define I_CNT 8192
#define DIM 64
#define BAND 16                   // rows per band (per block per step)
#define CHUNKW 512                // cols owned by one block (fixed)
#define NMEMB 16                  // members (column chunks)
#define NGRP 64                   // groups (concurrent bands per step)
#define NSTEP 16                  // bands per group sweep
#define LDSW 516                  // floats; writes 2-way (free), reads at LDS minimum
#define NEG_LOG2E (-1.4426950408889634f)

typedef __bf16 bf16x8 __attribute__((ext_vector_type(8)));
typedef float f32x4 __attribute__((ext_vector_type(4)));
typedef unsigned short ushort4v __attribute__((ext_vector_type(4)));

__device__ __forceinline__ unsigned short f32_to_bf16_rtn(float f) {
    unsigned int b = __float_as_uint(f);
    b += 0x7fffu + ((b >> 16) & 1u);
    return (unsigned short)(b >> 16);
}

// Prep: blocks [0, 2048) convert Q1 -> bf16; blocks [2048, ...) scan seg_ids
// for segment boundaries. UNCHANGED from champion.
__global__ __launch_bounds__(256) void prep_kernel(
    const float* __restrict__ Q1, unsigned short* __restrict__ Q1bf,
    const int* __restrict__ segs, int nnz, int* __restrict__ bounds)
{
    if (blockIdx.x < 2048) {
        int i = blockIdx.x * 256 + threadIdx.x;   // covers I_CNT*DIM = 524288
        Q1bf[i] = f32_to_bf16_rtn(Q1[i]);
    } else {
        int i = (blockIdx.x - 2048) * 256 + threadIdx.x;
        if (i >= nnz) return;
        if (i == 0) bounds[segs[0]] = 0;
        else if (segs[i] != segs[i - 1]) bounds[segs[i]] = i;
        if (i == nnz - 1) bounds[U_CNT] = nnz;
    }
}

// One wave per user, quarter-wave per item (R12 vectorized gather).
// UNCHANGED from champion.
__global__ __launch_bounds__(256) void pfull_kernel(
    const float* __restrict__ Q2, const float* __restrict__ P,
    const int* __restrict__ items, const int* __restrict__ bounds,
    unsigned short* __restrict__ Pbf)
{
    const int u = (blockIdx.x * 256 + threadIdx.x) >> 6;
    const int lane = threadIdx.x & 63;
    if (u >= U_CNT) return;
    const int qg = lane >> 4;       // quarter-group: which item in a 4-pack
    const int ql = lane & 15;       // dim slot: 16 lanes x f32x4 = 64 dims

    const int start = bounds[u];
    const int end   = bounds[u + 1];
    const int cnt   = end - start;  // guaranteed >= 1

    f32x4 acc0 = {0.f, 0.f, 0.f, 0.f}, acc1 = {0.f, 0.f, 0.f, 0.f};
    int j = start + qg;
    for (; j + 4 < end; j += 8) {
        int i0 = items[j], i1 = items[j + 4];
        f32x4 v0 = *reinterpret_cast<const f32x4*>(&Q2[i0 * DIM + ql * 4]);
        f32x4 v1 = *reinterpret_cast<const f32x4*>(&Q2[i1 * DIM + ql * 4]);
        acc0 += v0;
        acc1 += v1;
    }
    if (j < end)
        acc0 += *reinterpret_cast<const f32x4*>(&Q2[items[j] * DIM + ql * 4]);
    f32x4 acc = acc0 + acc1;

    // Reduce across the 4 quarter-groups (lanes l, l+16, l+32, l+48).
#pragma unroll
    for (int e = 0; e < 4; ++e) {
        acc[e] += __shfl_xor(acc[e], 16, 64);
        acc[e] += __shfl_xor(acc[e], 32, 64);
    }

    if (qg == 0) {
        f32x4 pv = *reinterpret_cast<const f32x4*>(&P[u * DIM + ql * 4]);
        float rs = rsqrtf((float)cnt);
        ushort4v o;
#pragma unroll
        for (int e = 0; e < 4; ++e)
            o[e] = f32_to_bf16_rtn(acc[e] * rs + pv[e]);
        *reinterpret_cast<ushort4v*>(&Pbf[u * DIM + ql * 4]) = o;
    }
}

// Coordinated-window GEMM + sigmoid. Granule x2 experiment, occupancy FIXED:
// grid stays 1024 blocks = 64 groups x 16 members (4 blocks/CU), each block
// owns a fixed 512-col chunk and sweeps 16 bands (band = group + s*64).
// Window per step = 64x16 = 1024 rows = 32 MB linear. Store: per row, 2
// back-to-back f32x4 nt instrs = 2 KB contiguous per row-visit (vs R14's
// 1 KB). VGPR held <=128 for 4 waves/SIMD: acc computed in two halves of 4,
// __launch_bounds__(256,4) pins the allocator. LDS [16][516] = 33 KB x4 =
// 132 KB/CU. Isolates granule from R15's occupancy confound.
__global__ __launch_bounds__(256, 4) void gemm_sig_kernel(
    const unsigned short* __restrict__ Abf, const unsigned short* __restrict__ Bbf,
    const float* __restrict__ bu, const float* __restrict__ bi,
    float* __restrict__ out)
{
    const int lane = threadIdx.x & 63;
    const int wid  = threadIdx.x >> 6;      // 0..3: 128-col sub-band within chunk
    const int r = lane & 15, g = lane >> 4;
    const int member = blockIdx.x & (NMEMB - 1);   // fixed 512-col chunk
    const int group  = blockIdx.x >> 4;            // 0..63
    const int colbase = member * CHUNKW;
    const int col0 = colbase + wid * 128;

    __shared__ float lds[BAND][LDSW];       // 33 KB, block-wide

    // B fragments + bi: loaded ONCE, register-resident for the whole kernel.
    bf16x8 b[8][2];
    float bi_f[8];
#pragma unroll
    for (int nf = 0; nf < 8; ++nf) {
        bi_f[nf] = bi[col0 + nf * 16 + r] + 0.05f;   // fold the +0.05 here
#pragma unroll
        for (int ks = 0; ks < 2; ++ks)
            b[nf][ks] = *reinterpret_cast<const bf16x8*>(
                &Bbf[(col0 + nf * 16 + r) * DIM + ks * 32 + g * 8]);
    }

    for (int s = 0; s < NSTEP; ++s) {
        const int band = (group + s * NGRP) * BAND;

        // A fragment for this band (rows band..band+15), both K-steps.
        bf16x8 a[2];
#pragma unroll
        for (int ks = 0; ks < 2; ++ks)
            a[ks] = *reinterpret_cast<const bf16x8*>(
                &Abf[(band + r) * DIM + ks * 32 + g * 8]);

        float bu_g[4];
#pragma unroll
        for (int j = 0; j < 4; ++j) bu_g[j] = bu[band + g * 4 + j];

        // Two halves of 4 N-fragments each: acc stays at 16 VGPRs.
#pragma unroll
        for (int half = 0; half < 2; ++half) {
            f32x4 acc[4] = {};
#pragma unroll
            for (int ks = 0; ks < 2; ++ks)
#pragma unroll
                for (int nf = 0; nf < 4; ++nf)
                    acc[nf] = __builtin_amdgcn_mfma_f32_16x16x32_bf16(
                        a[ks], b[half * 4 + nf][ks], acc[nf], 0, 0, 0);

            // Sigmoid in acc layout (row = g*4+j,
            // col = wid*128 + half*64 + nf*16 + r), into the block-wide tile.
#pragma unroll
            for (int nf = 0; nf < 4; ++nf)
#pragma unroll
                for (int j = 0; j < 4; ++j) {
                    float x = (acc[nf][j] + bu_g[j] + bi_f[half * 4 + nf]) * NEG_LOG2E;
                    float e = __builtin_amdgcn_exp2f(x);
                    float v = 5.f * __builtin_amdgcn_rcpf(1.f + e);
                    lds[g * 4 + j][wid * 128 + half * 64 + nf * 16 + r] = v;
                }
        }

        __syncthreads();

        // Store phase: wave wid owns rows wid*4..+3. Per row: 2 back-to-back
        // f32x4 instructions = 2 KB fully contiguous, nontemporal.
#pragma unroll
        for (int i = 0; i < 4; ++i) {
            const int row = wid * 4 + i;
            float* dst = &out[(size_t)(band + row) * I_CNT + colbase];
#pragma unroll
            for (int q = 0; q < 2; ++q) {
                f32x4 v = *reinterpret_cast<const f32x4*>(&lds[row][q * 256 + lane * 4]);
                __builtin_nontemporal_store(v,
                    reinterpret_cast<f32x4*>(dst + q * 256 + lane * 4));
            }
        }

        __syncthreads();   // protect tile reuse by next step
    }
}

extern "C" void kernel_launch(void* const* d_in, const int* in_sizes, int n_in,
                              void* d_out, int out_size, void* d_ws, size_t ws_size,
                              hipStream_t stream)
{
    const float* Q1 = (const float*)d_in[0];
    const float* Q2 = (const float*)d_in[1];
    const float* P  = (const float*)d_in[2];
    const float* bu = (const float*)d_in[3];
    const float* bi = (const float*)d_in[4];
    const int* items = (const int*)d_in[5];
    const int* segs  = (const int*)d_in[6];
    const int nnz = in_sizes[5];

    unsigned short* Pbf  = (unsigned short*)d_ws;            // 2 MB
    unsigned short* Q1bf = Pbf + U_CNT * DIM;                // 1 MB
    int* bounds = (int*)(Q1bf + I_CNT * DIM);                // 64 KB + 4 B

    int boundsBlocks = (nnz + 255) / 256;
    prep_kernel<<<2048 + boundsBlocks, 256, 0, stream>>>(Q1, Q1bf, segs, nnz, bounds);
    pfull_kernel<<<U_CNT / 4, 256, 0, stream>>>(Q2, P, items, bounds, Pbf);
    // 64 groups x 16 members = 1024 blocks; each block sweeps NSTEP=16 bands.
    gemm_sig_kernel<<<NGRP * NMEMB, 256, 0, stream>>>(Pbf, Q1bf, bu, bi, (float*)d_out);
}

// Round 17
// 114.929 us; speedup vs baseline: 1.1368x; 1.1368x over previous
//
#include <hip/hip_runtime.h>

#define U_CNT 16384
#define I_CNT 8192
#define DIM 64
#define BAND 16                   // rows per band (per block per step)
#define CHUNK 256                 // cols owned by one block (fixed)
#define NSTEP 32                  // bands per group sweep
#define LDS_STRIDE 260            // floats; writes 2-way (free), reads clean
#define NEG_LOG2E (-1.4426950408889634f)

typedef __bf16 bf16x8 __attribute__((ext_vector_type(8)));
typedef float f32x4 __attribute__((ext_vector_type(4)));
typedef unsigned short ushort4v __attribute__((ext_vector_type(4)));

__device__ __forceinline__ unsigned short f32_to_bf16_rtn(float f) {
    unsigned int b = __float_as_uint(f);
    b += 0x7fffu + ((b >> 16) & 1u);
    return (unsigned short)(b >> 16);
}

// Prep: blocks [0, 2048) convert Q1 -> bf16; blocks [2048, ...) scan seg_ids
// for segment boundaries. UNCHANGED from champion (R14).
__global__ __launch_bounds__(256) void prep_kernel(
    const float* __restrict__ Q1, unsigned short* __restrict__ Q1bf,
    const int* __restrict__ segs, int nnz, int* __restrict__ bounds)
{
    if (blockIdx.x < 2048) {
        int i = blockIdx.x * 256 + threadIdx.x;   // covers I_CNT*DIM = 524288
        Q1bf[i] = f32_to_bf16_rtn(Q1[i]);
    } else {
        int i = (blockIdx.x - 2048) * 256 + threadIdx.x;
        if (i >= nnz) return;
        if (i == 0) bounds[segs[0]] = 0;
        else if (segs[i] != segs[i - 1]) bounds[segs[i]] = i;
        if (i == nnz - 1) bounds[U_CNT] = nnz;
    }
}

// One wave per user, quarter-wave per item (R12 vectorized gather).
// UNCHANGED from champion (R14).
__global__ __launch_bounds__(256) void pfull_kernel(
    const float* __restrict__ Q2, const float* __restrict__ P,
    const int* __restrict__ items, const int* __restrict__ bounds,
    unsigned short* __restrict__ Pbf)
{
    const int u = (blockIdx.x * 256 + threadIdx.x) >> 6;
    const int lane = threadIdx.x & 63;
    if (u >= U_CNT) return;
    const int qg = lane >> 4;       // quarter-group: which item in a 4-pack
    const int ql = lane & 15;       // dim slot: 16 lanes x f32x4 = 64 dims

    const int start = bounds[u];
    const int end   = bounds[u + 1];
    const int cnt   = end - start;  // guaranteed >= 1

    f32x4 acc0 = {0.f, 0.f, 0.f, 0.f}, acc1 = {0.f, 0.f, 0.f, 0.f};
    int j = start + qg;
    for (; j + 4 < end; j += 8) {
        int i0 = items[j], i1 = items[j + 4];
        f32x4 v0 = *reinterpret_cast<const f32x4*>(&Q2[i0 * DIM + ql * 4]);
        f32x4 v1 = *reinterpret_cast<const f32x4*>(&Q2[i1 * DIM + ql * 4]);
        acc0 += v0;
        acc1 += v1;
    }
    if (j < end)
        acc0 += *reinterpret_cast<const f32x4*>(&Q2[items[j] * DIM + ql * 4]);
    f32x4 acc = acc0 + acc1;

    // Reduce across the 4 quarter-groups (lanes l, l+16, l+32, l+48).
#pragma unroll
    for (int e = 0; e < 4; ++e) {
        acc[e] += __shfl_xor(acc[e], 16, 64);
        acc[e] += __shfl_xor(acc[e], 32, 64);
    }

    if (qg == 0) {
        f32x4 pv = *reinterpret_cast<const f32x4*>(&P[u * DIM + ql * 4]);
        float rs = rsqrtf((float)cnt);
        ushort4v o;
#pragma unroll
        for (int e = 0; e < 4; ++e)
            o[e] = f32_to_bf16_rtn(acc[e] * rs + pv[e]);
        *reinterpret_cast<ushort4v*>(&Pbf[u * DIM + ql * 4]) = o;
    }
}

// Coordinated-window GEMM + sigmoid. SINGLE CHANGE vs the 114.8us champion
// (R14): DOUBLE-BUFFERED LDS tile + ONE barrier per step (was single tile +
// two barriers). R14's trailing barrier forced the compiler's
// s_waitcnt vmcnt(0) drain of the 8 nt stores INSIDE each step (~0.7us/step
// of serialized compute+drain = the ~22us gap to the 78us pure-store floor).
// Now: compute -> lds[p]; barrier; store from lds[p]; next step computes
// into lds[p^1] with no trailing barrier — step-s stores drain during
// step-s+1 compute. Race-free: waves' reads of lds[p^1] happened before
// barrier(s), which every wave passed before computing into lds[p^1].
// Geometry/stores byte-identical to R14: 1024 blocks (32 groups x 32
// members), fixed 256-col chunk, 1 KB contiguous nt store per row.
__global__ __launch_bounds__(256) void gemm_sig_kernel(
    const unsigned short* __restrict__ Abf, const unsigned short* __restrict__ Bbf,
    const float* __restrict__ bu, const float* __restrict__ bi,
    float* __restrict__ out)
{
    const int lane = threadIdx.x & 63;
    const int wid  = threadIdx.x >> 6;      // 0..3: 64-col sub-band within chunk
    const int r = lane & 15, g = lane >> 4;
    const int member = blockIdx.x & 31;     // fixed col chunk
    const int group  = blockIdx.x >> 5;     // 0..31
    const int colbase = member * CHUNK;
    const int col0 = colbase + wid * 64;

    __shared__ float lds[2][BAND][LDS_STRIDE];   // 33.3 KB, double-buffered

    // B fragments + bi: loaded ONCE, register-resident for the whole kernel.
    bf16x8 b[4][2];
    float bi_f[4];
#pragma unroll
    for (int nf = 0; nf < 4; ++nf) {
        bi_f[nf] = bi[col0 + nf * 16 + r] + 0.05f;   // fold the +0.05 here
#pragma unroll
        for (int ks = 0; ks < 2; ++ks)
            b[nf][ks] = *reinterpret_cast<const bf16x8*>(
                &Bbf[(col0 + nf * 16 + r) * DIM + ks * 32 + g * 8]);
    }

    for (int s = 0; s < NSTEP; ++s) {
        const int band = (group + s * 32) * BAND;
        const int p = s & 1;

        // A fragment for this band (rows band..band+15), both K-steps.
        bf16x8 a[2];
#pragma unroll
        for (int ks = 0; ks < 2; ++ks)
            a[ks] = *reinterpret_cast<const bf16x8*>(
                &Abf[(band + r) * DIM + ks * 32 + g * 8]);

        float bu_g[4];
#pragma unroll
        for (int j = 0; j < 4; ++j) bu_g[j] = bu[band + g * 4 + j];

        f32x4 acc[4] = {};
#pragma unroll
        for (int ks = 0; ks < 2; ++ks)
#pragma unroll
            for (int nf = 0; nf < 4; ++nf)
                acc[nf] = __builtin_amdgcn_mfma_f32_16x16x32_bf16(
                    a[ks], b[nf][ks], acc[nf], 0, 0, 0);

        // Sigmoid in acc layout (row = g*4+j, col = wid*64 + nf*16 + r),
        // write into buffer p of the block-wide tile.
#pragma unroll
        for (int nf = 0; nf < 4; ++nf)
#pragma unroll
            for (int j = 0; j < 4; ++j) {
                float x = (acc[nf][j] + bu_g[j] + bi_f[nf]) * NEG_LOG2E;
                float e = __builtin_amdgcn_exp2f(x);
                float v = 5.f * __builtin_amdgcn_rcpf(1.f + e);
                lds[p][g * 4 + j][wid * 64 + nf * 16 + r] = v;
            }

        __syncthreads();   // the ONLY barrier per step

        // Store phase: wave wid owns rows wid*4..+3. ONE instruction per
        // row: 64 lanes x f32x4 = 1 KB fully contiguous, nontemporal.
        // No trailing barrier: these drain during step s+1's compute.
#pragma unroll
        for (int i = 0; i < 4; ++i) {
            const int row = wid * 4 + i;
            f32x4 v = *reinterpret_cast<const f32x4*>(&lds[p][row][lane * 4]);
            __builtin_nontemporal_store(v, reinterpret_cast<f32x4*>(
                &out[(size_t)(band + row) * I_CNT + colbase + lane * 4]));
        }
    }
}

extern "C" void kernel_launch(void* const* d_in, const int* in_sizes, int n_in,
                              void* d_out, int out_size, void* d_ws, size_t ws_size,
                              hipStream_t stream)
{
    const float* Q1 = (const float*)d_in[0];
    const float* Q2 = (const float*)d_in[1];
    const float* P  = (const float*)d_in[2];
    const float* bu = (const float*)d_in[3];
    const float* bi = (const float*)d_in[4];
    const int* items = (const int*)d_in[5];
    const int* segs  = (const int*)d_in[6];
    const int nnz = in_sizes[5];

    unsigned short* Pbf  = (unsigned short*)d_ws;            // 2 MB
    unsigned short* Q1bf = Pbf + U_CNT * DIM;                // 1 MB
    int* bounds = (int*)(Q1bf + I_CNT * DIM);                // 64 KB + 4 B

    int boundsBlocks = (nnz + 255) / 256;
    prep_kernel<<<2048 + boundsBlocks, 256, 0, stream>>>(Q1, Q1bf, segs, nnz, bounds);
    pfull_kernel<<<U_CNT / 4, 256, 0, stream>>>(Q2, P, items, bounds, Pbf);
    // 32 groups x 32 members = 1024 blocks; each block sweeps NSTEP=32 bands.
    gemm_sig_kernel<<<32 * 32, 256, 0, stream>>>(Pbf, Q1bf, bu, bi, (float*)d_out);
}